// Round 10
// baseline (488.488 us; speedup 1.0000x reference)
//
#include <hip/hip_runtime.h>
#include <hip/hip_bf16.h>

// GatedConv: N=50000, E=800000, D=128, G=64, 2 layers.
// Round 9: dispatch-count 13 -> 9 and CSR-build restructure.
//  - Padded-bucket direct scatter (capacity 4096/bucket, atomic reservation)
//    removes bucket_hist + bucket_scan; bucket_sort emits row_start/row_end.
//  - pack_all also zeroes cur/outsum/pool counter (memset gone).
//  - pool finalize fused via last-block counter (pool2 gone); finalize reads
//    outsum with atomicAdd(p,0.f) to stay on the device-coherent path (G16).
//  - aggregate: quarter-wave per node (16 lanes, 16 edges in flight, no
//    cross-lane reduce) for 4x node TLP per wave.
// Requires N <= 131072 (17-bit src pack), NB <= 512.

#define DTHREADS 256
#define BSHIFT 7
#define BNODES 128
#define BCAP 4096

typedef __attribute__((ext_vector_type(8))) short bf16x8;
typedef __attribute__((ext_vector_type(4))) float f32x4;

__device__ __forceinline__ float sigf(float x) { return 1.0f / (1.0f + __expf(-x)); }
__device__ __forceinline__ float tanhfast(float x) { return 1.0f - 2.0f / (1.0f + __expf(2.0f * x)); }

__device__ __forceinline__ unsigned short f2bf_rne(float x) {
  unsigned int u = __float_as_uint(x);
  u += 0x7fff + ((u >> 16) & 1);
  return (unsigned short)(u >> 16);
}
__device__ __forceinline__ float bf2f(unsigned int lo16) {
  return __uint_as_float(lo16 << 16);
}

// ---- embed gather: hb[n,:] = bf16(embed[node_ids[n],:]) ------------------
__global__ __launch_bounds__(DTHREADS) void gather_kernel(
    const float* __restrict__ embed, const int* __restrict__ node_ids,
    unsigned short* __restrict__ hb, int N) {
  int idx = blockIdx.x * DTHREADS + threadIdx.x;
  if (idx >= N * 32) return;
  int n = idx >> 5;
  int c = (idx & 31) * 4;
  int v = node_ids[n];
  float4 val = *(const float4*)&embed[(size_t)v * 128 + c];
  unsigned short b[4] = {f2bf_rne(val.x), f2bf_rne(val.y), f2bf_rne(val.z), f2bf_rne(val.w)};
  *(ushort4*)&hb[(size_t)n * 128 + c] = *(ushort4*)b;
}

// ---- pack all weights + zero-init scratch --------------------------------
// seg 0: wpk_hh <- bf16(w_hh[j][k]) ; seg 1+L: wpk_wc[L] <- bf16(conv[L]@w_ih^T)
// Also zeroes cur[NB], outsum[osz], pool counter (replaces memsets).
__global__ __launch_bounds__(DTHREADS) void pack_all_kernel(
    const float* __restrict__ w_hh, const float* __restrict__ conv_w,
    const float* __restrict__ w_ih, unsigned short* __restrict__ wpk_hh,
    unsigned short* __restrict__ wpk_wc, int nl,
    int* __restrict__ cur, int NB, float* __restrict__ outsum, int osz,
    int* __restrict__ pcnt) {
  int id = blockIdx.x * DTHREADS + threadIdx.x;
  if (id < NB) cur[id] = 0;
  if (id < osz) outsum[id] = 0.f;
  if (id == 0) *pcnt = 0;
  int seg = id / (384 * 128);
  if (seg > nl) return;
  int r = id - seg * (384 * 128);
  int f = r >> 3, i = r & 7;
  int l = f & 63;
  int s = (f >> 6) & 3;
  int t = (f >> 8) & 3;
  int jb = f >> 10;
  int j = jb * 64 + t * 16 + (l & 15);
  int k = s * 32 + (l >> 4) * 8 + i;
  float val;
  unsigned short* dst;
  if (seg == 0) {
    val = w_hh[j * 128 + k];
    dst = wpk_hh;
  } else {
    const float* conv = conv_w + (size_t)(seg - 1) * 128 * 128;
    float acc = 0.f;
    for (int d = 0; d < 128; d += 4) {
      float4 cv = *(const float4*)&conv[k * 128 + d];
      float4 wv = *(const float4*)&w_ih[j * 128 + d];
      acc += cv.x * wv.x + cv.y * wv.y + cv.z * wv.z + cv.w * wv.w;
    }
    val = acc;
    dst = wpk_wc + (size_t)(seg - 1) * 384 * 128;
  }
  dst[(size_t)f * 8 + i] = f2bf_rne(val);
}

// ---- direct bucket scatter into padded regions ---------------------------
// Per block: LDS local ranks, one global reservation per (block,bucket),
// grouped writes into bucket region [b*BCAP, b*BCAP+cur[b]).
__global__ __launch_bounds__(DTHREADS) void bucket_scatter_kernel(
    const int* __restrict__ src, const int* __restrict__ dst,
    int* __restrict__ cur, unsigned int* __restrict__ ebuf, int E, int NB) {
  __shared__ int lc[512];
  __shared__ int lbs[512];
  int tid = threadIdx.x;
  for (int i = tid; i < NB; i += DTHREADS) lc[i] = 0;
  __syncthreads();
  int base = blockIdx.x * 4096;
  int rank[16];
  #pragma unroll
  for (int q = 0; q < 16; ++q) {
    int e = base + q * 256 + tid;
    if (e < E) rank[q] = atomicAdd(&lc[dst[e] >> BSHIFT], 1);
  }
  __syncthreads();
  for (int i = tid; i < NB; i += DTHREADS) {
    int c = lc[i];
    lbs[i] = c ? atomicAdd(&cur[i], c) : 0;
  }
  __syncthreads();
  #pragma unroll
  for (int q = 0; q < 16; ++q) {
    int e = base + q * 256 + tid;
    if (e < E) {
      int d = dst[e];
      int b = d >> BSHIFT;
      int slot = lbs[b] + rank[q];
      if (slot < BCAP)
        ebuf[(size_t)b * BCAP + slot] =
            (unsigned int)src[e] | ((unsigned int)(d & (BNODES - 1)) << 17);
    }
  }
}

// ---- per-bucket counting sort -> row_start/row_end + csr_src -------------
__global__ __launch_bounds__(DTHREADS) void bucket_sort_kernel(
    const unsigned int* __restrict__ ebuf, const int* __restrict__ cur,
    int* __restrict__ row_start, int* __restrict__ row_end,
    int* __restrict__ csr_src, int N) {
  __shared__ int cnt[BNODES];
  __shared__ int sc[BNODES];
  const int tid = threadIdx.x;
  const int b = blockIdx.x;
  const int count = min(cur[b], BCAP);
  const unsigned int* eb = ebuf + (size_t)b * BCAP;
  int* cs = csr_src + (size_t)b * BCAP;
  if (tid < BNODES) cnt[tid] = 0;
  __syncthreads();
  for (int i = tid; i < count; i += DTHREADS)
    atomicAdd(&cnt[eb[i] >> 17], 1);
  __syncthreads();
  if (tid < BNODES) sc[tid] = cnt[tid];
  __syncthreads();
  #pragma unroll
  for (int off = 1; off < BNODES; off <<= 1) {
    int t = 0;
    if (tid < BNODES && tid >= off) t = sc[tid - off];
    __syncthreads();
    if (tid < BNODES) sc[tid] += t;
    __syncthreads();
  }
  if (tid < BNODES) {
    int excl = sc[tid] - cnt[tid];
    int n = b * BNODES + tid;
    if (n < N) {
      row_start[n] = b * BCAP + excl;
      row_end[n] = b * BCAP + sc[tid];
    }
    cnt[tid] = excl;  // reuse as cursor
  }
  __syncthreads();
  for (int i = tid; i < count; i += DTHREADS) {
    unsigned int pk = eb[i];
    int slot = atomicAdd(&cnt[pk >> 17], 1);
    cs[slot] = (int)(pk & 0x1FFFFu);
  }
}

// ---- aggregate: quarter-wave (16 lanes) per node, 16 edges in flight -----
// Lane owns 16B chunk c of the node's 256B row; no cross-lane reduce.
__global__ __launch_bounds__(DTHREADS) void aggregate_kernel(
    const unsigned short* __restrict__ hb, const int* __restrict__ row_start,
    const int* __restrict__ row_end, const int* __restrict__ csr_src,
    unsigned short* __restrict__ agg, int N) {
  int node = (blockIdx.x * DTHREADS + threadIdx.x) >> 4;
  if (node >= N) return;
  int c = threadIdx.x & 15;
  int s = row_start[node], e = row_end[node];
  float acc[8] = {0.f, 0.f, 0.f, 0.f, 0.f, 0.f, 0.f, 0.f};
  for (int i = s; i < e; i += 16) {
    int idx[16];
    #pragma unroll
    for (int q = 0; q < 16; ++q) {
      int ii = i + q;
      idx[q] = csr_src[ii < e ? ii : s];
    }
    uint4 d[16];
    #pragma unroll
    for (int q = 0; q < 16; ++q)
      d[q] = *(const uint4*)&hb[(size_t)idx[q] * 128 + c * 8];
    #pragma unroll
    for (int q = 0; q < 16; ++q) {
      if (i + q < e) {
        const unsigned int* dp = (const unsigned int*)&d[q];
        #pragma unroll
        for (int u = 0; u < 4; ++u) {
          acc[2 * u]     += bf2f(dp[u] & 0xffffu);
          acc[2 * u + 1] += bf2f(dp[u] >> 16);
        }
      }
    }
  }
  unsigned int o[4];
  #pragma unroll
  for (int q = 0; q < 4; ++q)
    o[q] = (unsigned int)f2bf_rne(acc[2 * q]) | ((unsigned int)f2bf_rne(acc[2 * q + 1]) << 16);
  *(uint4*)&agg[(size_t)node * 128 + c * 8] = *(uint4*)o;
}

// ---- persistent fused GRU (weights in VGPRs, register prefetch) ----------
__global__ __launch_bounds__(512, 2) void fused_gru_kernel(
    const unsigned short* __restrict__ aggb, const unsigned short* __restrict__ wpk_wc,
    const unsigned short* __restrict__ wpk_hh, const float* __restrict__ b_ih,
    const float* __restrict__ b_hh, unsigned short* __restrict__ hb,
    int N, int nchunks) {
  __shared__ __align__(16) unsigned short Ag[32 * 128];  // 8 KB
  __shared__ __align__(16) unsigned short Hs[32 * 128];  // 8 KB
  const int tid = threadIdx.x;
  const int wv = tid >> 6, lane = tid & 63;
  const int lm = lane & 15, quad = lane >> 4;

  bf16x8 BI[3][4], BH[3][4];
  #pragma unroll
  for (int g = 0; g < 3; ++g) {
    int jb = g * 2 + (wv >> 2);
    int t = wv & 3;
    #pragma unroll
    for (int s = 0; s < 4; ++s) {
      size_t f = ((size_t)(jb * 4 + t) * 4 + s) * 64 + lane;
      BI[g][s] = *(const bf16x8*)&wpk_wc[f * 8];
      BH[g][s] = *(const bf16x8*)&wpk_hh[f * 8];
    }
  }

  const int jc = wv * 16 + lm;
  const float bir = b_ih[jc], biz = b_ih[128 + jc], bin_ = b_ih[256 + jc];
  const float bhr = b_hh[jc], bhz = b_hh[128 + jc], bhn = b_hh[256 + jc];
  const int c0 = jc >> 3, ej = jc & 7;

  const int srow = tid >> 4, scol = tid & 15;
  const int sdc = (scol ^ (srow & 15)) * 8;

  int ci = blockIdx.x;
  uint4 va = make_uint4(0, 0, 0, 0), vh = make_uint4(0, 0, 0, 0);
  if (ci < nchunks) {
    int n = ci * 32 + srow;
    if (n < N) {
      va = *(const uint4*)&aggb[(size_t)n * 128 + scol * 8];
      vh = *(const uint4*)&hb[(size_t)n * 128 + scol * 8];
    }
  }

  for (; ci < nchunks; ci += gridDim.x) {
    *(uint4*)&Ag[srow * 128 + sdc] = va;
    *(uint4*)&Hs[srow * 128 + sdc] = vh;
    __syncthreads();

    int cn = ci + gridDim.x;
    va = make_uint4(0, 0, 0, 0); vh = make_uint4(0, 0, 0, 0);
    if (cn < nchunks) {
      int n = cn * 32 + srow;
      if (n < N) {
        va = *(const uint4*)&aggb[(size_t)n * 128 + scol * 8];
        vh = *(const uint4*)&hb[(size_t)n * 128 + scol * 8];
      }
    }

    f32x4 accI[2][3], accH[2][3];
    #pragma unroll
    for (int mi = 0; mi < 2; ++mi)
      #pragma unroll
      for (int g = 0; g < 3; ++g) {
        accI[mi][g] = (f32x4){0.f, 0.f, 0.f, 0.f};
        accH[mi][g] = (f32x4){0.f, 0.f, 0.f, 0.f};
      }

    #pragma unroll
    for (int s = 0; s < 4; ++s) {
      bf16x8 afA[2], afH[2];
      #pragma unroll
      for (int mi = 0; mi < 2; ++mi) {
        int m = mi * 16 + lm;
        int chunk = (s * 4 + quad) ^ (m & 15);
        afA[mi] = *(const bf16x8*)&Ag[m * 128 + chunk * 8];
        afH[mi] = *(const bf16x8*)&Hs[m * 128 + chunk * 8];
      }
      #pragma unroll
      for (int g = 0; g < 3; ++g)
        #pragma unroll
        for (int mi = 0; mi < 2; ++mi) {
          accI[mi][g] = __builtin_amdgcn_mfma_f32_16x16x32_bf16(afA[mi], BI[g][s], accI[mi][g], 0, 0, 0);
          accH[mi][g] = __builtin_amdgcn_mfma_f32_16x16x32_bf16(afH[mi], BH[g][s], accH[mi][g], 0, 0, 0);
        }
    }

    const int n0 = ci * 32;
    #pragma unroll
    for (int mi = 0; mi < 2; ++mi) {
      #pragma unroll
      for (int r = 0; r < 4; ++r) {
        int row = mi * 16 + quad * 4 + r;
        int n = n0 + row;
        if (n >= N) continue;
        float ir = accI[mi][0][r] + bir;
        float iz = accI[mi][1][r] + biz;
        float in_ = accI[mi][2][r] + bin_;
        float hr = accH[mi][0][r] + bhr;
        float hz = accH[mi][1][r] + bhz;
        float hn = accH[mi][2][r] + bhn;
        float rr = sigf(ir + hr);
        float zz = sigf(iz + hz);
        float nn = tanhfast(in_ + rr * hn);
        float hold = bf2f((unsigned int)Hs[row * 128 + ((c0 ^ (row & 15)) * 8) + ej]);
        hb[(size_t)n * 128 + jc] = f2bf_rne((1.f - zz) * nn + zz * hold);
      }
    }
    __syncthreads();
  }
}

// ---- mean pool: partial sums + last-block finalize -----------------------
__device__ __forceinline__ int lbound(const int* a, int n, int key) {
  int lo = 0, hi = n;
  while (lo < hi) {
    int mid = (lo + hi) >> 1;
    if (a[mid] < key) lo = mid + 1; else hi = mid;
  }
  return lo;
}

__global__ __launch_bounds__(DTHREADS) void pool_kernel(
    const unsigned short* __restrict__ hb, const int* __restrict__ batch,
    float* __restrict__ outsum, float* __restrict__ out, int* __restrict__ pcnt,
    int N, int G, int nblocks) {
  int b = blockIdx.x;
  int c = threadIdx.x & 127;
  int half = threadIdx.x >> 7;
  int nbeg = b * 64;
  int nend = min(nbeg + 64, N);
  float acc = 0.f;
  int cur = -1;
  for (int n = nbeg + half; n < nend; n += 2) {
    int g = batch[n];
    if (g != cur) {
      if (cur >= 0) atomicAdd(&outsum[(size_t)cur * 128 + c], acc);
      acc = 0.f;
      cur = g;
    }
    acc += bf2f((unsigned int)hb[(size_t)n * 128 + c]);
  }
  if (cur >= 0) atomicAdd(&outsum[(size_t)cur * 128 + c], acc);

  __threadfence();
  __shared__ int last;
  if (threadIdx.x == 0) last = atomicAdd(pcnt, 1);
  __syncthreads();
  if (last == nblocks - 1) {
    for (int i = threadIdx.x; i < G * 128; i += DTHREADS) {
      int g = i >> 7;
      int lo = lbound(batch, N, g);
      int hi = lbound(batch, N, g + 1);
      // atomic read keeps us on the device-coherent path (cross-XCD safe)
      float s = atomicAdd(&outsum[i], 0.f);
      out[i] = s / (float)max(hi - lo, 1);
    }
  }
}

extern "C" void kernel_launch(void* const* d_in, const int* in_sizes, int n_in,
                              void* d_out, int out_size, void* d_ws, size_t ws_size,
                              hipStream_t stream) {
  const int* node_ids = (const int*)d_in[0];
  const int* edge_index = (const int*)d_in[1];
  const int* batch = (const int*)d_in[2];
  const float* embed = (const float*)d_in[4];
  const float* conv_w = (const float*)d_in[5];
  const float* w_ih = (const float*)d_in[6];
  const float* w_hh = (const float*)d_in[7];
  const float* b_ih = (const float*)d_in[8];
  const float* b_hh = (const float*)d_in[9];
  float* out = (float*)d_out;

  const int N = in_sizes[0];
  const int E = in_sizes[1] / 2;
  const int G = out_size / 128;
  const int NUM_LAYERS = in_sizes[5] / (128 * 128);
  const int NB = (N + BNODES - 1) >> BSHIFT;  // 391; requires NB<=512

  const int* e_src = edge_index;
  const int* e_dst = edge_index + E;

  // ---- workspace carve-up (16B aligned) ----
  char* p = (char*)d_ws;
  unsigned short* hb = (unsigned short*)p;    p += (size_t)N * 128 * 2;
  unsigned short* aggb = (unsigned short*)p;  p += (size_t)N * 128 * 2;
  float* outsum = (float*)p;                  p += (size_t)G * 128 * 4;
  unsigned short* wpk_hh = (unsigned short*)p; p += (size_t)384 * 128 * 2;
  unsigned short* wpk_wc = (unsigned short*)p; p += (size_t)NUM_LAYERS * 384 * 128 * 2;
  int* cur = (int*)p;        p += 512 * 4;
  int* pcnt = (int*)p;       p += 16;
  int* row_start = (int*)p;  p += (size_t)N * 4;
  int* row_end = (int*)p;    p += (size_t)N * 4;
  unsigned int* ebuf = (unsigned int*)p;  p += (size_t)NB * BCAP * 4;
  int* csr_src = (int*)p;    p += (size_t)NB * BCAP * 4;

  const int nEB = (E + 4095) / 4096;

  // pack weights + zero cur/outsum/pcnt (one dispatch)
  {
    int total = (NUM_LAYERS + 1) * 384 * 128;
    pack_all_kernel<<<(total + DTHREADS - 1) / DTHREADS, DTHREADS, 0, stream>>>(
        w_hh, conv_w, w_ih, wpk_hh, wpk_wc, NUM_LAYERS, cur, NB, outsum, G * 128, pcnt);
  }

  // bucketized CSR build (padded buckets; reused by both layers)
  bucket_scatter_kernel<<<nEB, DTHREADS, 0, stream>>>(e_src, e_dst, cur, ebuf, E, NB);
  bucket_sort_kernel<<<NB, DTHREADS, 0, stream>>>(ebuf, cur, row_start, row_end, csr_src, N);

  gather_kernel<<<(N * 32 + DTHREADS - 1) / DTHREADS, DTHREADS, 0, stream>>>(embed, node_ids, hb, N);

  const int nchunks = (N + 31) / 32;
  for (int L = 0; L < NUM_LAYERS; ++L) {
    aggregate_kernel<<<((size_t)N * 16 + DTHREADS - 1) / DTHREADS, DTHREADS, 0, stream>>>(
        hb, row_start, row_end, csr_src, aggb, N);
    fused_gru_kernel<<<512, 512, 0, stream>>>(
        aggb, wpk_wc + (size_t)L * 384 * 128, wpk_hh, b_ih, b_hh, hb, N, nchunks);
  }

  const int pblocks = (N + 63) / 64;
  pool_kernel<<<pblocks, DTHREADS, 0, stream>>>(hb, batch, outsum, out, pcnt, N, G, pblocks);
}

// Round 11
// 285.713 us; speedup vs baseline: 1.7097x; 1.7097x over previous
//
#include <hip/hip_runtime.h>
#include <hip/hip_bf16.h>

// GatedConv: N=50000, E=800000, D=128, G=64, 2 layers.
// Round 10: revert ONLY round-9's pool fusion (the single finalize block ran
// 229us of serialized binary searches while 255 CUs idled). Back to the
// two-dispatch pool. Keep round-9's wins: padded-bucket direct scatter
// (no hist/scan), quarter-wave aggregate (16 edges in flight/node),
// pack_all zero-init folding.
// Requires N <= 131072 (17-bit src pack), NB <= 512.

#define DTHREADS 256
#define BSHIFT 7
#define BNODES 128
#define BCAP 4096

typedef __attribute__((ext_vector_type(8))) short bf16x8;
typedef __attribute__((ext_vector_type(4))) float f32x4;

__device__ __forceinline__ float sigf(float x) { return 1.0f / (1.0f + __expf(-x)); }
__device__ __forceinline__ float tanhfast(float x) { return 1.0f - 2.0f / (1.0f + __expf(2.0f * x)); }

__device__ __forceinline__ unsigned short f2bf_rne(float x) {
  unsigned int u = __float_as_uint(x);
  u += 0x7fff + ((u >> 16) & 1);
  return (unsigned short)(u >> 16);
}
__device__ __forceinline__ float bf2f(unsigned int lo16) {
  return __uint_as_float(lo16 << 16);
}

// ---- embed gather: hb[n,:] = bf16(embed[node_ids[n],:]) ------------------
__global__ __launch_bounds__(DTHREADS) void gather_kernel(
    const float* __restrict__ embed, const int* __restrict__ node_ids,
    unsigned short* __restrict__ hb, int N) {
  int idx = blockIdx.x * DTHREADS + threadIdx.x;
  if (idx >= N * 32) return;
  int n = idx >> 5;
  int c = (idx & 31) * 4;
  int v = node_ids[n];
  float4 val = *(const float4*)&embed[(size_t)v * 128 + c];
  unsigned short b[4] = {f2bf_rne(val.x), f2bf_rne(val.y), f2bf_rne(val.z), f2bf_rne(val.w)};
  *(ushort4*)&hb[(size_t)n * 128 + c] = *(ushort4*)b;
}

// ---- pack all weights + zero-init scratch --------------------------------
__global__ __launch_bounds__(DTHREADS) void pack_all_kernel(
    const float* __restrict__ w_hh, const float* __restrict__ conv_w,
    const float* __restrict__ w_ih, unsigned short* __restrict__ wpk_hh,
    unsigned short* __restrict__ wpk_wc, int nl,
    int* __restrict__ cur, int NB, float* __restrict__ outsum, int osz) {
  int id = blockIdx.x * DTHREADS + threadIdx.x;
  if (id < NB) cur[id] = 0;
  if (id < osz) outsum[id] = 0.f;
  int seg = id / (384 * 128);
  if (seg > nl) return;
  int r = id - seg * (384 * 128);
  int f = r >> 3, i = r & 7;
  int l = f & 63;
  int s = (f >> 6) & 3;
  int t = (f >> 8) & 3;
  int jb = f >> 10;
  int j = jb * 64 + t * 16 + (l & 15);
  int k = s * 32 + (l >> 4) * 8 + i;
  float val;
  unsigned short* dst;
  if (seg == 0) {
    val = w_hh[j * 128 + k];
    dst = wpk_hh;
  } else {
    const float* conv = conv_w + (size_t)(seg - 1) * 128 * 128;
    float acc = 0.f;
    for (int d = 0; d < 128; d += 4) {
      float4 cv = *(const float4*)&conv[k * 128 + d];
      float4 wv = *(const float4*)&w_ih[j * 128 + d];
      acc += cv.x * wv.x + cv.y * wv.y + cv.z * wv.z + cv.w * wv.w;
    }
    val = acc;
    dst = wpk_wc + (size_t)(seg - 1) * 384 * 128;
  }
  dst[(size_t)f * 8 + i] = f2bf_rne(val);
}

// ---- direct bucket scatter into padded regions ---------------------------
__global__ __launch_bounds__(DTHREADS) void bucket_scatter_kernel(
    const int* __restrict__ src, const int* __restrict__ dst,
    int* __restrict__ cur, unsigned int* __restrict__ ebuf, int E, int NB) {
  __shared__ int lc[512];
  __shared__ int lbs[512];
  int tid = threadIdx.x;
  for (int i = tid; i < NB; i += DTHREADS) lc[i] = 0;
  __syncthreads();
  int base = blockIdx.x * 4096;
  int rank[16];
  #pragma unroll
  for (int q = 0; q < 16; ++q) {
    int e = base + q * 256 + tid;
    if (e < E) rank[q] = atomicAdd(&lc[dst[e] >> BSHIFT], 1);
  }
  __syncthreads();
  for (int i = tid; i < NB; i += DTHREADS) {
    int c = lc[i];
    lbs[i] = c ? atomicAdd(&cur[i], c) : 0;
  }
  __syncthreads();
  #pragma unroll
  for (int q = 0; q < 16; ++q) {
    int e = base + q * 256 + tid;
    if (e < E) {
      int d = dst[e];
      int b = d >> BSHIFT;
      int slot = lbs[b] + rank[q];
      if (slot < BCAP)
        ebuf[(size_t)b * BCAP + slot] =
            (unsigned int)src[e] | ((unsigned int)(d & (BNODES - 1)) << 17);
    }
  }
}

// ---- per-bucket counting sort -> row_start/row_end + csr_src -------------
__global__ __launch_bounds__(DTHREADS) void bucket_sort_kernel(
    const unsigned int* __restrict__ ebuf, const int* __restrict__ cur,
    int* __restrict__ row_start, int* __restrict__ row_end,
    int* __restrict__ csr_src, int N) {
  __shared__ int cnt[BNODES];
  __shared__ int sc[BNODES];
  const int tid = threadIdx.x;
  const int b = blockIdx.x;
  const int count = min(cur[b], BCAP);
  const unsigned int* eb = ebuf + (size_t)b * BCAP;
  int* cs = csr_src + (size_t)b * BCAP;
  if (tid < BNODES) cnt[tid] = 0;
  __syncthreads();
  for (int i = tid; i < count; i += DTHREADS)
    atomicAdd(&cnt[eb[i] >> 17], 1);
  __syncthreads();
  if (tid < BNODES) sc[tid] = cnt[tid];
  __syncthreads();
  #pragma unroll
  for (int off = 1; off < BNODES; off <<= 1) {
    int t = 0;
    if (tid < BNODES && tid >= off) t = sc[tid - off];
    __syncthreads();
    if (tid < BNODES) sc[tid] += t;
    __syncthreads();
  }
  if (tid < BNODES) {
    int excl = sc[tid] - cnt[tid];
    int n = b * BNODES + tid;
    if (n < N) {
      row_start[n] = b * BCAP + excl;
      row_end[n] = b * BCAP + sc[tid];
    }
    cnt[tid] = excl;  // reuse as cursor
  }
  __syncthreads();
  for (int i = tid; i < count; i += DTHREADS) {
    unsigned int pk = eb[i];
    int slot = atomicAdd(&cnt[pk >> 17], 1);
    cs[slot] = (int)(pk & 0x1FFFFu);
  }
}

// ---- aggregate: quarter-wave (16 lanes) per node, 16 edges in flight -----
__global__ __launch_bounds__(DTHREADS) void aggregate_kernel(
    const unsigned short* __restrict__ hb, const int* __restrict__ row_start,
    const int* __restrict__ row_end, const int* __restrict__ csr_src,
    unsigned short* __restrict__ agg, int N) {
  int node = (blockIdx.x * DTHREADS + threadIdx.x) >> 4;
  if (node >= N) return;
  int c = threadIdx.x & 15;
  int s = row_start[node], e = row_end[node];
  float acc[8] = {0.f, 0.f, 0.f, 0.f, 0.f, 0.f, 0.f, 0.f};
  for (int i = s; i < e; i += 16) {
    int idx[16];
    #pragma unroll
    for (int q = 0; q < 16; ++q) {
      int ii = i + q;
      idx[q] = csr_src[ii < e ? ii : s];
    }
    uint4 d[16];
    #pragma unroll
    for (int q = 0; q < 16; ++q)
      d[q] = *(const uint4*)&hb[(size_t)idx[q] * 128 + c * 8];
    #pragma unroll
    for (int q = 0; q < 16; ++q) {
      if (i + q < e) {
        const unsigned int* dp = (const unsigned int*)&d[q];
        #pragma unroll
        for (int u = 0; u < 4; ++u) {
          acc[2 * u]     += bf2f(dp[u] & 0xffffu);
          acc[2 * u + 1] += bf2f(dp[u] >> 16);
        }
      }
    }
  }
  unsigned int o[4];
  #pragma unroll
  for (int q = 0; q < 4; ++q)
    o[q] = (unsigned int)f2bf_rne(acc[2 * q]) | ((unsigned int)f2bf_rne(acc[2 * q + 1]) << 16);
  *(uint4*)&agg[(size_t)node * 128 + c * 8] = *(uint4*)o;
}

// ---- persistent fused GRU (weights in VGPRs, register prefetch) ----------
__global__ __launch_bounds__(512, 2) void fused_gru_kernel(
    const unsigned short* __restrict__ aggb, const unsigned short* __restrict__ wpk_wc,
    const unsigned short* __restrict__ wpk_hh, const float* __restrict__ b_ih,
    const float* __restrict__ b_hh, unsigned short* __restrict__ hb,
    int N, int nchunks) {
  __shared__ __align__(16) unsigned short Ag[32 * 128];  // 8 KB
  __shared__ __align__(16) unsigned short Hs[32 * 128];  // 8 KB
  const int tid = threadIdx.x;
  const int wv = tid >> 6, lane = tid & 63;
  const int lm = lane & 15, quad = lane >> 4;

  bf16x8 BI[3][4], BH[3][4];
  #pragma unroll
  for (int g = 0; g < 3; ++g) {
    int jb = g * 2 + (wv >> 2);
    int t = wv & 3;
    #pragma unroll
    for (int s = 0; s < 4; ++s) {
      size_t f = ((size_t)(jb * 4 + t) * 4 + s) * 64 + lane;
      BI[g][s] = *(const bf16x8*)&wpk_wc[f * 8];
      BH[g][s] = *(const bf16x8*)&wpk_hh[f * 8];
    }
  }

  const int jc = wv * 16 + lm;
  const float bir = b_ih[jc], biz = b_ih[128 + jc], bin_ = b_ih[256 + jc];
  const float bhr = b_hh[jc], bhz = b_hh[128 + jc], bhn = b_hh[256 + jc];
  const int c0 = jc >> 3, ej = jc & 7;

  const int srow = tid >> 4, scol = tid & 15;
  const int sdc = (scol ^ (srow & 15)) * 8;

  int ci = blockIdx.x;
  uint4 va = make_uint4(0, 0, 0, 0), vh = make_uint4(0, 0, 0, 0);
  if (ci < nchunks) {
    int n = ci * 32 + srow;
    if (n < N) {
      va = *(const uint4*)&aggb[(size_t)n * 128 + scol * 8];
      vh = *(const uint4*)&hb[(size_t)n * 128 + scol * 8];
    }
  }

  for (; ci < nchunks; ci += gridDim.x) {
    *(uint4*)&Ag[srow * 128 + sdc] = va;
    *(uint4*)&Hs[srow * 128 + sdc] = vh;
    __syncthreads();

    int cn = ci + gridDim.x;
    va = make_uint4(0, 0, 0, 0); vh = make_uint4(0, 0, 0, 0);
    if (cn < nchunks) {
      int n = cn * 32 + srow;
      if (n < N) {
        va = *(const uint4*)&aggb[(size_t)n * 128 + scol * 8];
        vh = *(const uint4*)&hb[(size_t)n * 128 + scol * 8];
      }
    }

    f32x4 accI[2][3], accH[2][3];
    #pragma unroll
    for (int mi = 0; mi < 2; ++mi)
      #pragma unroll
      for (int g = 0; g < 3; ++g) {
        accI[mi][g] = (f32x4){0.f, 0.f, 0.f, 0.f};
        accH[mi][g] = (f32x4){0.f, 0.f, 0.f, 0.f};
      }

    #pragma unroll
    for (int s = 0; s < 4; ++s) {
      bf16x8 afA[2], afH[2];
      #pragma unroll
      for (int mi = 0; mi < 2; ++mi) {
        int m = mi * 16 + lm;
        int chunk = (s * 4 + quad) ^ (m & 15);
        afA[mi] = *(const bf16x8*)&Ag[m * 128 + chunk * 8];
        afH[mi] = *(const bf16x8*)&Hs[m * 128 + chunk * 8];
      }
      #pragma unroll
      for (int g = 0; g < 3; ++g)
        #pragma unroll
        for (int mi = 0; mi < 2; ++mi) {
          accI[mi][g] = __builtin_amdgcn_mfma_f32_16x16x32_bf16(afA[mi], BI[g][s], accI[mi][g], 0, 0, 0);
          accH[mi][g] = __builtin_amdgcn_mfma_f32_16x16x32_bf16(afH[mi], BH[g][s], accH[mi][g], 0, 0, 0);
        }
    }

    const int n0 = ci * 32;
    #pragma unroll
    for (int mi = 0; mi < 2; ++mi) {
      #pragma unroll
      for (int r = 0; r < 4; ++r) {
        int row = mi * 16 + quad * 4 + r;
        int n = n0 + row;
        if (n >= N) continue;
        float ir = accI[mi][0][r] + bir;
        float iz = accI[mi][1][r] + biz;
        float in_ = accI[mi][2][r] + bin_;
        float hr = accH[mi][0][r] + bhr;
        float hz = accH[mi][1][r] + bhz;
        float hn = accH[mi][2][r] + bhn;
        float rr = sigf(ir + hr);
        float zz = sigf(iz + hz);
        float nn = tanhfast(in_ + rr * hn);
        float hold = bf2f((unsigned int)Hs[row * 128 + ((c0 ^ (row & 15)) * 8) + ej]);
        hb[(size_t)n * 128 + jc] = f2bf_rne((1.f - zz) * nn + zz * hold);
      }
    }
    __syncthreads();
  }
}

// ---- two-stage mean pool over bf16 h-state -------------------------------
__global__ __launch_bounds__(DTHREADS) void pool1_kernel(
    const unsigned short* __restrict__ hb, const int* __restrict__ batch,
    float* __restrict__ outsum, int N) {
  int b = blockIdx.x;
  int c = threadIdx.x & 127;
  int half = threadIdx.x >> 7;
  int nbeg = b * 64;
  int nend = min(nbeg + 64, N);
  float acc = 0.f;
  int cur = -1;
  for (int n = nbeg + half; n < nend; n += 2) {
    int g = batch[n];
    if (g != cur) {
      if (cur >= 0) atomicAdd(&outsum[(size_t)cur * 128 + c], acc);
      acc = 0.f;
      cur = g;
    }
    acc += bf2f((unsigned int)hb[(size_t)n * 128 + c]);
  }
  if (cur >= 0) atomicAdd(&outsum[(size_t)cur * 128 + c], acc);
}

__device__ __forceinline__ int lbound(const int* a, int n, int key) {
  int lo = 0, hi = n;
  while (lo < hi) {
    int mid = (lo + hi) >> 1;
    if (a[mid] < key) lo = mid + 1; else hi = mid;
  }
  return lo;
}

__global__ __launch_bounds__(128) void pool2_kernel(
    const float* __restrict__ outsum, const int* __restrict__ batch,
    float* __restrict__ out, int N) {
  int g = blockIdx.x;
  int c = threadIdx.x;
  int lo = lbound(batch, N, g);
  int hi = lbound(batch, N, g + 1);
  out[(size_t)g * 128 + c] = outsum[(size_t)g * 128 + c] / (float)max(hi - lo, 1);
}

extern "C" void kernel_launch(void* const* d_in, const int* in_sizes, int n_in,
                              void* d_out, int out_size, void* d_ws, size_t ws_size,
                              hipStream_t stream) {
  const int* node_ids = (const int*)d_in[0];
  const int* edge_index = (const int*)d_in[1];
  const int* batch = (const int*)d_in[2];
  const float* embed = (const float*)d_in[4];
  const float* conv_w = (const float*)d_in[5];
  const float* w_ih = (const float*)d_in[6];
  const float* w_hh = (const float*)d_in[7];
  const float* b_ih = (const float*)d_in[8];
  const float* b_hh = (const float*)d_in[9];
  float* out = (float*)d_out;

  const int N = in_sizes[0];
  const int E = in_sizes[1] / 2;
  const int G = out_size / 128;
  const int NUM_LAYERS = in_sizes[5] / (128 * 128);
  const int NB = (N + BNODES - 1) >> BSHIFT;  // 391; requires NB<=512

  const int* e_src = edge_index;
  const int* e_dst = edge_index + E;

  // ---- workspace carve-up (16B aligned) ----
  char* p = (char*)d_ws;
  unsigned short* hb = (unsigned short*)p;    p += (size_t)N * 128 * 2;
  unsigned short* aggb = (unsigned short*)p;  p += (size_t)N * 128 * 2;
  float* outsum = (float*)p;                  p += (size_t)G * 128 * 4;
  unsigned short* wpk_hh = (unsigned short*)p; p += (size_t)384 * 128 * 2;
  unsigned short* wpk_wc = (unsigned short*)p; p += (size_t)NUM_LAYERS * 384 * 128 * 2;
  int* cur = (int*)p;        p += 512 * 4;
  int* row_start = (int*)p;  p += (size_t)N * 4;
  int* row_end = (int*)p;    p += (size_t)N * 4;
  unsigned int* ebuf = (unsigned int*)p;  p += (size_t)NB * BCAP * 4;
  int* csr_src = (int*)p;    p += (size_t)NB * BCAP * 4;

  const int nEB = (E + 4095) / 4096;

  // pack weights + zero cur/outsum (one dispatch)
  {
    int total = (NUM_LAYERS + 1) * 384 * 128;
    pack_all_kernel<<<(total + DTHREADS - 1) / DTHREADS, DTHREADS, 0, stream>>>(
        w_hh, conv_w, w_ih, wpk_hh, wpk_wc, NUM_LAYERS, cur, NB, outsum, G * 128);
  }

  // bucketized CSR build (padded buckets; reused by both layers)
  bucket_scatter_kernel<<<nEB, DTHREADS, 0, stream>>>(e_src, e_dst, cur, ebuf, E, NB);
  bucket_sort_kernel<<<NB, DTHREADS, 0, stream>>>(ebuf, cur, row_start, row_end, csr_src, N);

  gather_kernel<<<(N * 32 + DTHREADS - 1) / DTHREADS, DTHREADS, 0, stream>>>(embed, node_ids, hb, N);

  const int nchunks = (N + 31) / 32;
  for (int L = 0; L < NUM_LAYERS; ++L) {
    aggregate_kernel<<<((size_t)N * 16 + DTHREADS - 1) / DTHREADS, DTHREADS, 0, stream>>>(
        hb, row_start, row_end, csr_src, aggb, N);
    fused_gru_kernel<<<512, 512, 0, stream>>>(
        aggb, wpk_wc + (size_t)L * 384 * 128, wpk_hh, b_ih, b_hh, hb, N, nchunks);
  }

  const int pblocks = (N + 63) / 64;
  pool1_kernel<<<pblocks, DTHREADS, 0, stream>>>(hb, batch, outsum, N);
  pool2_kernel<<<G, 128, 0, stream>>>(outsum, batch, out, N);
}